// Round 4
// baseline (2236.042 us; speedup 1.0000x reference)
//
#include <hip/hip_runtime.h>
#include <math.h>

#define NN 20000
#define NE 320000
#define ET (NE + NN)
#define FIN 17
#define DD 64
#define DOUTC 32
#define NMIDL 18
#define SLOPE 0.2f
#define BN_EPS 1e-5f

// ---------------- preprocessing: CSR by dst ----------------

__global__ void k_init(int* __restrict__ deg, float* __restrict__ s0, float* __restrict__ s1) {
    int i = blockIdx.x * blockDim.x + threadIdx.x;
    if (i < NN) deg[i] = 1;              // self-loop
    if (i < 128) { s0[i] = 0.f; s1[i] = 0.f; }
}

__global__ void k_hist(const int* __restrict__ dst, int* __restrict__ deg) {
    int i = blockIdx.x * blockDim.x + threadIdx.x;
    if (i < NE) atomicAdd(&deg[dst[i]], 1);
}

__global__ __launch_bounds__(1024) void k_scan(const int* __restrict__ deg,
                                               int* __restrict__ row_ptr,
                                               int* __restrict__ cursor) {
    __shared__ int sarr[1024];
    int t = threadIdx.x;
    const int CH = 20;  // 1024*20 >= 20000
    int base = t * CH;
    int sum = 0;
    for (int j = 0; j < CH; ++j) {
        int idx = base + j;
        if (idx < NN) sum += deg[idx];
    }
    sarr[t] = sum;
    __syncthreads();
    for (int off = 1; off < 1024; off <<= 1) {
        int v = (t >= off) ? sarr[t - off] : 0;
        __syncthreads();
        sarr[t] += v;
        __syncthreads();
    }
    int run = sarr[t] - sum;  // exclusive prefix
    for (int j = 0; j < CH; ++j) {
        int idx = base + j;
        if (idx < NN) {
            row_ptr[idx] = run;
            cursor[idx] = run;
            run += deg[idx];
        }
    }
    if (t == 0) row_ptr[NN] = ET;
}

__global__ void k_scatter(const int* __restrict__ src, const int* __restrict__ dst,
                          int* __restrict__ cursor, int* __restrict__ edge_src) {
    int i = blockIdx.x * blockDim.x + threadIdx.x;
    if (i < NE) {
        int d = dst[i];
        int pos = atomicAdd(&cursor[d], 1);
        edge_src[pos] = src[i];
    } else if (i < ET) {
        int v = i - NE;
        int pos = atomicAdd(&cursor[v], 1);
        edge_src[pos] = v;
    }
}

// ---------------- dual GEMM: W in VGPRs, 4 nodes per wave (ILP), h rows via s_load ----------------
// Lane owns one output column of the concat [Wl | Wr]. 4 nodes share one
// contiguous 4*DIN-float uniform region -> chunked scalar loads, 4 independent
// FMA accumulators per lane.

template<int DIN, int DCOLS>
__global__ __launch_bounds__(256) void k_gemm3(const float* __restrict__ hin,
                                               const float* __restrict__ Wl, const float* __restrict__ bl,
                                               const float* __restrict__ Wr, const float* __restrict__ br,
                                               float* __restrict__ xl, float* __restrict__ xr) {
    constexpr int CG = (2 * DCOLS) / 64;   // column groups per node: 4 (DCOLS=128) or 2 (DCOLS=64)
    constexpr int NSETS = 4 / CG;          // node-sets per block: 1 or 2
    constexpr int NPB = NSETS * 4;         // nodes per block-iteration
    int wave = __builtin_amdgcn_readfirstlane(threadIdx.x >> 6);
    int lane = threadIdx.x & 63;
    int cg = wave % CG;
    int nset = wave / CG;
    int col = cg * 64 + lane;              // 0 .. 2*DCOLS-1
    bool isl = col < DCOLS;
    const float* W = isl ? Wl : Wr;
    float* xo = isl ? xl : xr;
    int cw = col & (DCOLS - 1);
    float wreg[DIN];
    #pragma unroll
    for (int k = 0; k < DIN; ++k) wreg[k] = W[k * DCOLS + cw];
    float bias = (isl ? bl : br)[cw];

    for (int n0 = blockIdx.x * NPB + nset * 4; n0 < NN; n0 += gridDim.x * NPB) {
        const float* h0 = hin + (size_t)n0 * DIN;   // 4 contiguous rows, wave-uniform
        float a0 = 0.f, a1 = 0.f, a2 = 0.f, a3 = 0.f;
        #pragma unroll 16
        for (int k = 0; k < DIN; ++k) {
            float wk = wreg[k];
            a0 = fmaf(h0[k],           wk, a0);
            a1 = fmaf(h0[DIN + k],     wk, a1);
            a2 = fmaf(h0[2 * DIN + k], wk, a2);
            a3 = fmaf(h0[3 * DIN + k], wk, a3);
        }
        xo[(size_t)(n0 + 0) * DCOLS + cw] = a0 + bias;
        xo[(size_t)(n0 + 1) * DCOLS + cw] = a1 + bias;
        xo[(size_t)(n0 + 2) * DCOLS + cw] = a2 + bias;
        xo[(size_t)(n0 + 3) * DCOLS + cw] = a3 + bias;
    }
}

// ---------------- edge aggregation: one wave per node (block=64), both heads ----------------
// Batch 8 edges (8 outstanding gathers); defer-max online softmax (THR=8).

template<int CPL>
__global__ __launch_bounds__(64) void k_edge3(const float* __restrict__ xl,
                                              const float* __restrict__ xr,
                                              const float* __restrict__ att,
                                              const float* __restrict__ bias,
                                              const int* __restrict__ row_ptr,
                                              const int* __restrict__ edge_src,
                                              float* __restrict__ g) {
    constexpr int HC = CPL * 32;   // channels per head
    constexpr int RS = 2 * HC;     // row stride (both heads)
    int lane = threadIdx.x;
    int node = blockIdx.x;
    int co = lane * CPL;
    float2 xrv, attc;
    if (CPL == 2) {
        xrv  = *(const float2*)&xr[node * RS + co];
        attc = *(const float2*)&att[co];
    } else {
        xrv.x = xr[node * RS + co]; xrv.y = 0.f;
        attc.x = att[co];           attc.y = 0.f;
    }
    int beg = row_ptr[node], end = row_ptr[node + 1];
    float m = -1e30f, s = 0.f;
    float2 o = {0.f, 0.f};

    for (int cb = beg; cb < end; cb += 64) {
        int idx = cb + lane;
        int eload = edge_src[idx < end ? idx : end - 1];
        int cnt = min(64, end - cb);
        for (int b = 0; b < cnt; b += 8) {
            int nb = min(8, cnt - b);
            float p[8]; float2 xv[8];
            #pragma unroll
            for (int j = 0; j < 8; ++j) {
                int u = __shfl(eload, b + (j < nb ? j : 0));
                float2 v;
                if (CPL == 2) v = *(const float2*)&xl[u * RS + co];
                else { v.x = xl[u * RS + co]; v.y = 0.f; }
                xv[j] = v;
                float tx = v.x + xrv.x, ty = v.y + xrv.y;
                tx = tx > 0.f ? tx : SLOPE * tx;
                ty = ty > 0.f ? ty : SLOPE * ty;
                float pp = tx * attc.x + ty * attc.y;
                #pragma unroll
                for (int msk = 16; msk; msk >>= 1) pp += __shfl_xor(pp, msk);
                p[j] = (j < nb) ? pp : -1e30f;
            }
            // defer-max: only rescale when the batch max exceeds m by THR=8
            float nm = fmaxf(fmaxf(fmaxf(p[0], p[1]), fmaxf(p[2], p[3])),
                             fmaxf(fmaxf(p[4], p[5]), fmaxf(p[6], p[7])));
            if (nm > m + 8.f) {
                float sc = __expf(m - nm);
                s *= sc; o.x *= sc; o.y *= sc;
                m = nm;
            }
            float w0 = __expf(p[0] - m), w1 = __expf(p[1] - m);
            float w2 = __expf(p[2] - m), w3 = __expf(p[3] - m);
            float w4 = __expf(p[4] - m), w5 = __expf(p[5] - m);
            float w6 = __expf(p[6] - m), w7 = __expf(p[7] - m);
            s += ((w0 + w1) + (w2 + w3)) + ((w4 + w5) + (w6 + w7));
            o.x += ((w0 * xv[0].x + w1 * xv[1].x) + (w2 * xv[2].x + w3 * xv[3].x))
                 + ((w4 * xv[4].x + w5 * xv[5].x) + (w6 * xv[6].x + w7 * xv[7].x));
            o.y += ((w0 * xv[0].y + w1 * xv[1].y) + (w2 * xv[2].y + w3 * xv[3].y))
                 + ((w4 * xv[4].y + w5 * xv[5].y) + (w6 * xv[6].y + w7 * xv[7].y));
        }
    }
    float inv = 1.f / s;
    float rx = o.x * inv, ry = o.y * inv;
    float ox = __shfl_xor(rx, 32);
    float oy = __shfl_xor(ry, 32);
    if (lane < 32) {
        if (CPL == 2) {
            float2 bv = *(const float2*)&bias[co];
            float2 outv = { 0.5f * (rx + ox) + bv.x, 0.5f * (ry + oy) + bv.y };
            *(float2*)&g[node * HC + co] = outv;
        } else {
            g[node * HC + co] = 0.5f * (rx + ox) + bias[co];
        }
    }
}

// ---------------- BN stats: sum & sumsq per feature ----------------

__global__ __launch_bounds__(256) void k_stat(const float* __restrict__ g, float* __restrict__ stats, int hc) {
    __shared__ float ls[4][64], ls2[4][64];
    int lane = threadIdx.x & 63;
    int grp  = threadIdx.x >> 6;
    bool act = lane < hc;
    float s = 0.f, s2 = 0.f;
    for (int row = blockIdx.x * 4 + grp; row < NN; row += gridDim.x * 4) {
        float v = act ? g[row * hc + lane] : 0.f;
        s += v; s2 += v * v;
    }
    ls[grp][lane] = s; ls2[grp][lane] = s2;
    __syncthreads();
    if (grp == 0 && act) {
        float ts  = ls[0][lane] + ls[1][lane] + ls[2][lane] + ls[3][lane];
        float ts2 = ls2[0][lane] + ls2[1][lane] + ls2[2][lane] + ls2[3][lane];
        atomicAdd(&stats[lane], ts);
        atomicAdd(&stats[64 + lane], ts2);
    }
}

// ---------------- BN apply + ReLU + optional residual; zero next stats ----------------

__global__ void k_apply(const float* __restrict__ g, const float* __restrict__ stats,
                        const float* __restrict__ gam, const float* __restrict__ bet,
                        const float* __restrict__ hin, float* __restrict__ hout,
                        int hc, int addres, float* __restrict__ statsNext) {
    if (blockIdx.x == 0 && threadIdx.x < 128) statsNext[threadIdx.x] = 0.f;
    int i = blockIdx.x * blockDim.x + threadIdx.x;
    int total = NN * hc;
    if (i >= total) return;
    int c = i & (hc - 1);
    float mu  = stats[c] * (1.f / NN);
    float var = stats[64 + c] * (1.f / NN) - mu * mu;
    float rsd = rsqrtf(var + BN_EPS);
    float v = gam[c] * (g[i] - mu) * rsd + bet[c];
    v = (v > 0.f) ? v : 0.f;
    hout[i] = (addres ? hin[i] : 0.f) + v;
}

// ---------------- final two heads ----------------

__global__ void k_head(const float* __restrict__ h,
                       const float* __restrict__ Wimp, const float* __restrict__ bimp,
                       const float* __restrict__ Wpol, const float* __restrict__ bpol,
                       float* __restrict__ out) {
    int n = blockIdx.x * blockDim.x + threadIdx.x;
    if (n >= NN) return;
    float a1 = bimp[0], a2 = bpol[0];
    for (int k = 0; k < DOUTC; ++k) {
        float hv = h[n * DOUTC + k];
        a1 += hv * Wimp[k];
        a2 += hv * Wpol[k];
    }
    out[n] = a1;
    out[NN + n] = 1.f / (1.f + expf(-a2));
}

// ---------------- launch ----------------

extern "C" void kernel_launch(void* const* d_in, const int* in_sizes, int n_in,
                              void* d_out, int out_size, void* d_ws, size_t ws_size,
                              hipStream_t stream) {
    const float* x    = (const float*)d_in[0];
    const int*   src  = (const int*)d_in[1];
    const int*   dst  = (const int*)d_in[2];
    const float* W0l  = (const float*)d_in[3];
    const float* b0l  = (const float*)d_in[4];
    const float* W0r  = (const float*)d_in[5];
    const float* b0r  = (const float*)d_in[6];
    const float* att0 = (const float*)d_in[7];
    const float* bias0= (const float*)d_in[8];
    const float* g0   = (const float*)d_in[9];
    const float* be0  = (const float*)d_in[10];
    const float* Wml  = (const float*)d_in[11];
    const float* bml  = (const float*)d_in[12];
    const float* Wmr  = (const float*)d_in[13];
    const float* bmr  = (const float*)d_in[14];
    const float* attm = (const float*)d_in[15];
    const float* biasm= (const float*)d_in[16];
    const float* gm   = (const float*)d_in[17];
    const float* bem  = (const float*)d_in[18];
    const float* WLl  = (const float*)d_in[19];
    const float* bLl  = (const float*)d_in[20];
    const float* WLr  = (const float*)d_in[21];
    const float* bLr  = (const float*)d_in[22];
    const float* attL = (const float*)d_in[23];
    const float* biasL= (const float*)d_in[24];
    const float* gL   = (const float*)d_in[25];
    const float* beL  = (const float*)d_in[26];
    const float* Wimp = (const float*)d_in[27];
    const float* bimp = (const float*)d_in[28];
    const float* Wpol = (const float*)d_in[29];
    const float* bpol = (const float*)d_in[30];
    float* out = (float*)d_out;

    char* w = (char*)d_ws;
    size_t off = 0;
    auto alloc = [&](size_t bytes) -> char* {
        char* p = w + off;
        off += (bytes + 511) & ~(size_t)511;
        return p;
    };
    int* deg      = (int*)alloc(NN * 4);
    int* cursor   = (int*)alloc(NN * 4);
    int* row_ptr  = (int*)alloc((NN + 1) * 4);
    int* edge_src = (int*)alloc(ET * 4);
    float* xl   = (float*)alloc((size_t)NN * 128 * 4);
    float* xr   = (float*)alloc((size_t)NN * 128 * 4);
    float* gbuf = (float*)alloc((size_t)NN * 64 * 4);
    float* hbuf = (float*)alloc((size_t)NN * 64 * 4);
    float* hL   = (float*)alloc((size_t)NN * 32 * 4);
    float* sb[2];
    sb[0] = (float*)alloc(512);
    sb[1] = (float*)alloc(512);

    // preprocessing
    k_init<<<(NN + 255) / 256, 256, 0, stream>>>(deg, sb[0], sb[1]);
    k_hist<<<(NE + 255) / 256, 256, 0, stream>>>(dst, deg);
    k_scan<<<1, 1024, 0, stream>>>(deg, row_ptr, cursor);
    k_scatter<<<(ET + 255) / 256, 256, 0, stream>>>(src, dst, cursor, edge_src);

    // layer 0: x [N,17] -> h [N,64]  (per-matrix cols = H*D = 128)
    k_gemm3<FIN, 128><<<1250, 256, 0, stream>>>(x, W0l, b0l, W0r, b0r, xl, xr);
    k_edge3<2><<<NN, 64, 0, stream>>>(xl, xr, att0, bias0, row_ptr, edge_src, gbuf);
    k_stat<<<256, 256, 0, stream>>>(gbuf, sb[0], DD);
    k_apply<<<(NN * DD + 255) / 256, 256, 0, stream>>>(gbuf, sb[0], g0, be0, nullptr, hbuf, DD, 0, sb[1]);

    // mid layers
    for (int i = 0; i < NMIDL; ++i) {
        int L = i + 1;
        const float* Wl = Wml + (size_t)i * DD * 128;
        const float* blp = bml + (size_t)i * 128;
        const float* Wr = Wmr + (size_t)i * DD * 128;
        const float* brp = bmr + (size_t)i * 128;
        const float* at = attm + (size_t)i * 128;
        const float* bs = biasm + (size_t)i * DD;
        const float* ga = gm + (size_t)i * DD;
        const float* be = bem + (size_t)i * DD;
        k_gemm3<DD, 128><<<1250, 256, 0, stream>>>(hbuf, Wl, blp, Wr, brp, xl, xr);
        k_edge3<2><<<NN, 64, 0, stream>>>(xl, xr, at, bs, row_ptr, edge_src, gbuf);
        k_stat<<<256, 256, 0, stream>>>(gbuf, sb[L & 1], DD);
        k_apply<<<(NN * DD + 255) / 256, 256, 0, stream>>>(gbuf, sb[L & 1], ga, be, hbuf, hbuf, DD, 1, sb[(L + 1) & 1]);
    }

    // final layer: h [N,64] -> hL [N,32]  (per-matrix cols = H*D_OUT = 64)
    {
        int L = 19;
        k_gemm3<DD, 64><<<1250, 256, 0, stream>>>(hbuf, WLl, bLl, WLr, bLr, xl, xr);
        k_edge3<1><<<NN, 64, 0, stream>>>(xl, xr, attL, biasL, row_ptr, edge_src, gbuf);
        k_stat<<<256, 256, 0, stream>>>(gbuf, sb[L & 1], DOUTC);
        k_apply<<<(NN * DOUTC + 255) / 256, 256, 0, stream>>>(gbuf, sb[L & 1], gL, beL, nullptr, hL, DOUTC, 0, sb[(L + 1) & 1]);
    }

    k_head<<<(NN + 255) / 256, 256, 0, stream>>>(hL, Wimp, bimp, Wpol, bpol, out);
}

// Round 7
// 1607.359 us; speedup vs baseline: 1.3911x; 1.3911x over previous
//
#include <hip/hip_runtime.h>
#include <math.h>

#define NN 20000
#define NE 320000
#define ET (NE + NN)
#define FIN 17
#define DD 64
#define DOUTC 32
#define NMIDL 18
#define SLOPE 0.2f
#define BN_EPS 1e-5f

// ---------------- preprocessing: CSR by dst ----------------

__global__ void k_init(int* __restrict__ deg, float* __restrict__ s0, float* __restrict__ s1) {
    int i = blockIdx.x * blockDim.x + threadIdx.x;
    if (i < NN) deg[i] = 1;              // self-loop
    if (i < 128) { s0[i] = 0.f; s1[i] = 0.f; }
}

__global__ void k_hist(const int* __restrict__ dst, int* __restrict__ deg) {
    int i = blockIdx.x * blockDim.x + threadIdx.x;
    if (i < NE) atomicAdd(&deg[dst[i]], 1);
}

__global__ __launch_bounds__(1024) void k_scan(const int* __restrict__ deg,
                                               int* __restrict__ row_ptr,
                                               int* __restrict__ cursor) {
    __shared__ int sarr[1024];
    int t = threadIdx.x;
    const int CH = 20;  // 1024*20 >= 20000
    int base = t * CH;
    int sum = 0;
    for (int j = 0; j < CH; ++j) {
        int idx = base + j;
        if (idx < NN) sum += deg[idx];
    }
    sarr[t] = sum;
    __syncthreads();
    for (int off = 1; off < 1024; off <<= 1) {
        int v = (t >= off) ? sarr[t - off] : 0;
        __syncthreads();
        sarr[t] += v;
        __syncthreads();
    }
    int run = sarr[t] - sum;  // exclusive prefix
    for (int j = 0; j < CH; ++j) {
        int idx = base + j;
        if (idx < NN) {
            row_ptr[idx] = run;
            cursor[idx] = run;
            run += deg[idx];
        }
    }
    if (t == 0) row_ptr[NN] = ET;
}

__global__ void k_scatter(const int* __restrict__ src, const int* __restrict__ dst,
                          int* __restrict__ cursor, int* __restrict__ edge_src) {
    int i = blockIdx.x * blockDim.x + threadIdx.x;
    if (i < NE) {
        int d = dst[i];
        int pos = atomicAdd(&cursor[d], 1);
        edge_src[pos] = src[i];
    } else if (i < ET) {
        int v = i - NE;
        int pos = atomicAdd(&cursor[v], 1);
        edge_src[pos] = v;
    }
}

// ---------------- dual GEMM: W in VGPRs (FULLY unrolled), 4 nodes per wave ----------------
// Lane owns one output column of the concat [Wl | Wr]. 4 nodes share one
// contiguous 4*DIN-float uniform region -> scalar loads, 4 independent
// FMA accumulators per lane. Inner loop MUST be fully unrolled so wreg[k]
// stays in registers (rule #20: runtime-indexed arrays spill to scratch —
// round 4: VGPR=36, 100MB scratch traffic, 62us vs 8us).

template<int DIN, int DCOLS>
__global__ __launch_bounds__(256) void k_gemm3(const float* __restrict__ hin,
                                               const float* __restrict__ Wl, const float* __restrict__ bl,
                                               const float* __restrict__ Wr, const float* __restrict__ br,
                                               float* __restrict__ xl, float* __restrict__ xr) {
    constexpr int CG = (2 * DCOLS) / 64;   // column groups per node: 4 (DCOLS=128) or 2 (DCOLS=64)
    constexpr int NSETS = 4 / CG;          // node-sets per block: 1 or 2
    constexpr int NPB = NSETS * 4;         // nodes per block-iteration
    int wave = __builtin_amdgcn_readfirstlane(threadIdx.x >> 6);
    int lane = threadIdx.x & 63;
    int cg = wave % CG;
    int nset = wave / CG;
    int col = cg * 64 + lane;              // 0 .. 2*DCOLS-1
    bool isl = col < DCOLS;
    const float* W = isl ? Wl : Wr;
    float* xo = isl ? xl : xr;
    int cw = col & (DCOLS - 1);
    float wreg[DIN];
    #pragma unroll
    for (int k = 0; k < DIN; ++k) wreg[k] = W[k * DCOLS + cw];
    float bias = (isl ? bl : br)[cw];

    for (int n0 = blockIdx.x * NPB + nset * 4; n0 < NN; n0 += gridDim.x * NPB) {
        const float* h0 = hin + (size_t)n0 * DIN;   // 4 contiguous rows, wave-uniform
        float a0 = 0.f, a1 = 0.f, a2 = 0.f, a3 = 0.f;
        #pragma unroll
        for (int k = 0; k < DIN; ++k) {
            float wk = wreg[k];
            a0 = fmaf(h0[k],           wk, a0);
            a1 = fmaf(h0[DIN + k],     wk, a1);
            a2 = fmaf(h0[2 * DIN + k], wk, a2);
            a3 = fmaf(h0[3 * DIN + k], wk, a3);
        }
        xo[(size_t)(n0 + 0) * DCOLS + cw] = a0 + bias;
        xo[(size_t)(n0 + 1) * DCOLS + cw] = a1 + bias;
        xo[(size_t)(n0 + 2) * DCOLS + cw] = a2 + bias;
        xo[(size_t)(n0 + 3) * DCOLS + cw] = a3 + bias;
    }
}

// ---------------- edge aggregation: one wave per node (block=64), both heads ----------------
// Batch 8 edges (8 outstanding gathers); defer-max online softmax (THR=8).

template<int CPL>
__global__ __launch_bounds__(64) void k_edge3(const float* __restrict__ xl,
                                              const float* __restrict__ xr,
                                              const float* __restrict__ att,
                                              const float* __restrict__ bias,
                                              const int* __restrict__ row_ptr,
                                              const int* __restrict__ edge_src,
                                              float* __restrict__ g) {
    constexpr int HC = CPL * 32;   // channels per head
    constexpr int RS = 2 * HC;     // row stride (both heads)
    int lane = threadIdx.x;
    int node = blockIdx.x;
    int co = lane * CPL;
    float2 xrv, attc;
    if (CPL == 2) {
        xrv  = *(const float2*)&xr[node * RS + co];
        attc = *(const float2*)&att[co];
    } else {
        xrv.x = xr[node * RS + co]; xrv.y = 0.f;
        attc.x = att[co];           attc.y = 0.f;
    }
    int beg = row_ptr[node], end = row_ptr[node + 1];
    float m = -1e30f, s = 0.f;
    float2 o = {0.f, 0.f};

    for (int cb = beg; cb < end; cb += 64) {
        int idx = cb + lane;
        int eload = edge_src[idx < end ? idx : end - 1];
        int cnt = min(64, end - cb);
        for (int b = 0; b < cnt; b += 8) {
            int nb = min(8, cnt - b);
            float p[8]; float2 xv[8];
            #pragma unroll
            for (int j = 0; j < 8; ++j) {
                int u = __shfl(eload, b + (j < nb ? j : 0));
                float2 v;
                if (CPL == 2) v = *(const float2*)&xl[u * RS + co];
                else { v.x = xl[u * RS + co]; v.y = 0.f; }
                xv[j] = v;
                float tx = v.x + xrv.x, ty = v.y + xrv.y;
                tx = tx > 0.f ? tx : SLOPE * tx;
                ty = ty > 0.f ? ty : SLOPE * ty;
                float pp = tx * attc.x + ty * attc.y;
                #pragma unroll
                for (int msk = 16; msk; msk >>= 1) pp += __shfl_xor(pp, msk);
                p[j] = (j < nb) ? pp : -1e30f;
            }
            // defer-max: only rescale when the batch max exceeds m by THR=8
            float nm = fmaxf(fmaxf(fmaxf(p[0], p[1]), fmaxf(p[2], p[3])),
                             fmaxf(fmaxf(p[4], p[5]), fmaxf(p[6], p[7])));
            if (nm > m + 8.f) {
                float sc = __expf(m - nm);
                s *= sc; o.x *= sc; o.y *= sc;
                m = nm;
            }
            float w0 = __expf(p[0] - m), w1 = __expf(p[1] - m);
            float w2 = __expf(p[2] - m), w3 = __expf(p[3] - m);
            float w4 = __expf(p[4] - m), w5 = __expf(p[5] - m);
            float w6 = __expf(p[6] - m), w7 = __expf(p[7] - m);
            s += ((w0 + w1) + (w2 + w3)) + ((w4 + w5) + (w6 + w7));
            o.x += ((w0 * xv[0].x + w1 * xv[1].x) + (w2 * xv[2].x + w3 * xv[3].x))
                 + ((w4 * xv[4].x + w5 * xv[5].x) + (w6 * xv[6].x + w7 * xv[7].x));
            o.y += ((w0 * xv[0].y + w1 * xv[1].y) + (w2 * xv[2].y + w3 * xv[3].y))
                 + ((w4 * xv[4].y + w5 * xv[5].y) + (w6 * xv[6].y + w7 * xv[7].y));
        }
    }
    float inv = 1.f / s;
    float rx = o.x * inv, ry = o.y * inv;
    float ox = __shfl_xor(rx, 32);
    float oy = __shfl_xor(ry, 32);
    if (lane < 32) {
        if (CPL == 2) {
            float2 bv = *(const float2*)&bias[co];
            float2 outv = { 0.5f * (rx + ox) + bv.x, 0.5f * (ry + oy) + bv.y };
            *(float2*)&g[node * HC + co] = outv;
        } else {
            g[node * HC + co] = 0.5f * (rx + ox) + bias[co];
        }
    }
}

// ---------------- BN stats: sum & sumsq per feature ----------------

__global__ __launch_bounds__(256) void k_stat(const float* __restrict__ g, float* __restrict__ stats, int hc) {
    __shared__ float ls[4][64], ls2[4][64];
    int lane = threadIdx.x & 63;
    int grp  = threadIdx.x >> 6;
    bool act = lane < hc;
    float s = 0.f, s2 = 0.f;
    for (int row = blockIdx.x * 4 + grp; row < NN; row += gridDim.x * 4) {
        float v = act ? g[row * hc + lane] : 0.f;
        s += v; s2 += v * v;
    }
    ls[grp][lane] = s; ls2[grp][lane] = s2;
    __syncthreads();
    if (grp == 0 && act) {
        float ts  = ls[0][lane] + ls[1][lane] + ls[2][lane] + ls[3][lane];
        float ts2 = ls2[0][lane] + ls2[1][lane] + ls2[2][lane] + ls2[3][lane];
        atomicAdd(&stats[lane], ts);
        atomicAdd(&stats[64 + lane], ts2);
    }
}

// ---------------- BN apply + ReLU + optional residual; zero next stats ----------------

__global__ void k_apply(const float* __restrict__ g, const float* __restrict__ stats,
                        const float* __restrict__ gam, const float* __restrict__ bet,
                        const float* __restrict__ hin, float* __restrict__ hout,
                        int hc, int addres, float* __restrict__ statsNext) {
    if (blockIdx.x == 0 && threadIdx.x < 128) statsNext[threadIdx.x] = 0.f;
    int i = blockIdx.x * blockDim.x + threadIdx.x;
    int total = NN * hc;
    if (i >= total) return;
    int c = i & (hc - 1);
    float mu  = stats[c] * (1.f / NN);
    float var = stats[64 + c] * (1.f / NN) - mu * mu;
    float rsd = rsqrtf(var + BN_EPS);
    float v = gam[c] * (g[i] - mu) * rsd + bet[c];
    v = (v > 0.f) ? v : 0.f;
    hout[i] = (addres ? hin[i] : 0.f) + v;
}

// ---------------- final two heads ----------------

__global__ void k_head(const float* __restrict__ h,
                       const float* __restrict__ Wimp, const float* __restrict__ bimp,
                       const float* __restrict__ Wpol, const float* __restrict__ bpol,
                       float* __restrict__ out) {
    int n = blockIdx.x * blockDim.x + threadIdx.x;
    if (n >= NN) return;
    float a1 = bimp[0], a2 = bpol[0];
    for (int k = 0; k < DOUTC; ++k) {
        float hv = h[n * DOUTC + k];
        a1 += hv * Wimp[k];
        a2 += hv * Wpol[k];
    }
    out[n] = a1;
    out[NN + n] = 1.f / (1.f + expf(-a2));
}

// ---------------- launch ----------------

extern "C" void kernel_launch(void* const* d_in, const int* in_sizes, int n_in,
                              void* d_out, int out_size, void* d_ws, size_t ws_size,
                              hipStream_t stream) {
    const float* x    = (const float*)d_in[0];
    const int*   src  = (const int*)d_in[1];
    const int*   dst  = (const int*)d_in[2];
    const float* W0l  = (const float*)d_in[3];
    const float* b0l  = (const float*)d_in[4];
    const float* W0r  = (const float*)d_in[5];
    const float* b0r  = (const float*)d_in[6];
    const float* att0 = (const float*)d_in[7];
    const float* bias0= (const float*)d_in[8];
    const float* g0   = (const float*)d_in[9];
    const float* be0  = (const float*)d_in[10];
    const float* Wml  = (const float*)d_in[11];
    const float* bml  = (const float*)d_in[12];
    const float* Wmr  = (const float*)d_in[13];
    const float* bmr  = (const float*)d_in[14];
    const float* attm = (const float*)d_in[15];
    const float* biasm= (const float*)d_in[16];
    const float* gm   = (const float*)d_in[17];
    const float* bem  = (const float*)d_in[18];
    const float* WLl  = (const float*)d_in[19];
    const float* bLl  = (const float*)d_in[20];
    const float* WLr  = (const float*)d_in[21];
    const float* bLr  = (const float*)d_in[22];
    const float* attL = (const float*)d_in[23];
    const float* biasL= (const float*)d_in[24];
    const float* gL   = (const float*)d_in[25];
    const float* beL  = (const float*)d_in[26];
    const float* Wimp = (const float*)d_in[27];
    const float* bimp = (const float*)d_in[28];
    const float* Wpol = (const float*)d_in[29];
    const float* bpol = (const float*)d_in[30];
    float* out = (float*)d_out;

    char* w = (char*)d_ws;
    size_t off = 0;
    auto alloc = [&](size_t bytes) -> char* {
        char* p = w + off;
        off += (bytes + 511) & ~(size_t)511;
        return p;
    };
    int* deg      = (int*)alloc(NN * 4);
    int* cursor   = (int*)alloc(NN * 4);
    int* row_ptr  = (int*)alloc((NN + 1) * 4);
    int* edge_src = (int*)alloc(ET * 4);
    float* xl   = (float*)alloc((size_t)NN * 128 * 4);
    float* xr   = (float*)alloc((size_t)NN * 128 * 4);
    float* gbuf = (float*)alloc((size_t)NN * 64 * 4);
    float* hbuf = (float*)alloc((size_t)NN * 64 * 4);
    float* hL   = (float*)alloc((size_t)NN * 32 * 4);
    float* sb[2];
    sb[0] = (float*)alloc(512);
    sb[1] = (float*)alloc(512);

    // preprocessing
    k_init<<<(NN + 255) / 256, 256, 0, stream>>>(deg, sb[0], sb[1]);
    k_hist<<<(NE + 255) / 256, 256, 0, stream>>>(dst, deg);
    k_scan<<<1, 1024, 0, stream>>>(deg, row_ptr, cursor);
    k_scatter<<<(ET + 255) / 256, 256, 0, stream>>>(src, dst, cursor, edge_src);

    // layer 0: x [N,17] -> h [N,64]  (per-matrix cols = H*D = 128)
    k_gemm3<FIN, 128><<<1250, 256, 0, stream>>>(x, W0l, b0l, W0r, b0r, xl, xr);
    k_edge3<2><<<NN, 64, 0, stream>>>(xl, xr, att0, bias0, row_ptr, edge_src, gbuf);
    k_stat<<<256, 256, 0, stream>>>(gbuf, sb[0], DD);
    k_apply<<<(NN * DD + 255) / 256, 256, 0, stream>>>(gbuf, sb[0], g0, be0, nullptr, hbuf, DD, 0, sb[1]);

    // mid layers
    for (int i = 0; i < NMIDL; ++i) {
        int L = i + 1;
        const float* Wl = Wml + (size_t)i * DD * 128;
        const float* blp = bml + (size_t)i * 128;
        const float* Wr = Wmr + (size_t)i * DD * 128;
        const float* brp = bmr + (size_t)i * 128;
        const float* at = attm + (size_t)i * 128;
        const float* bs = biasm + (size_t)i * DD;
        const float* ga = gm + (size_t)i * DD;
        const float* be = bem + (size_t)i * DD;
        k_gemm3<DD, 128><<<1250, 256, 0, stream>>>(hbuf, Wl, blp, Wr, brp, xl, xr);
        k_edge3<2><<<NN, 64, 0, stream>>>(xl, xr, at, bs, row_ptr, edge_src, gbuf);
        k_stat<<<256, 256, 0, stream>>>(gbuf, sb[L & 1], DD);
        k_apply<<<(NN * DD + 255) / 256, 256, 0, stream>>>(gbuf, sb[L & 1], ga, be, hbuf, hbuf, DD, 1, sb[(L + 1) & 1]);
    }

    // final layer: h [N,64] -> hL [N,32]  (per-matrix cols = H*D_OUT = 64)
    {
        int L = 19;
        k_gemm3<DD, 64><<<1250, 256, 0, stream>>>(hbuf, WLl, bLl, WLr, bLr, xl, xr);
        k_edge3<1><<<NN, 64, 0, stream>>>(xl, xr, attL, biasL, row_ptr, edge_src, gbuf);
        k_stat<<<256, 256, 0, stream>>>(gbuf, sb[L & 1], DOUTC);
        k_apply<<<(NN * DOUTC + 255) / 256, 256, 0, stream>>>(gbuf, sb[L & 1], gL, beL, nullptr, hL, DOUTC, 0, sb[(L + 1) & 1]);
    }

    k_head<<<(NN + 255) / 256, 256, 0, stream>>>(hL, Wimp, bimp, Wpol, bpol, out);
}

// Round 8
// 1368.010 us; speedup vs baseline: 1.6345x; 1.1750x over previous
//
#include <hip/hip_runtime.h>
#include <math.h>

#define NN 20000
#define NE 320000
#define ET (NE + NN)
#define FIN 17
#define DD 64
#define DOUTC 32
#define NMIDL 18
#define SLOPE 0.2f
#define BN_EPS 1e-5f

// ---------------- preprocessing: CSR by dst ----------------

__global__ void k_init(int* __restrict__ deg, float* __restrict__ part) {
    int i = blockIdx.x * blockDim.x + threadIdx.x;
    if (i < NN) deg[i] = 1;              // self-loop
    if (i < 2 * 64 * 128) part[i] = 0.f; // zero both stat-partial buffers
}

__global__ void k_hist(const int* __restrict__ dst, int* __restrict__ deg) {
    int i = blockIdx.x * blockDim.x + threadIdx.x;
    if (i < NE) atomicAdd(&deg[dst[i]], 1);
}

__global__ __launch_bounds__(1024) void k_scan(const int* __restrict__ deg,
                                               int* __restrict__ row_ptr,
                                               int* __restrict__ cursor) {
    __shared__ int sarr[1024];
    int t = threadIdx.x;
    const int CH = 20;  // 1024*20 >= 20000
    int base = t * CH;
    int sum = 0;
    for (int j = 0; j < CH; ++j) {
        int idx = base + j;
        if (idx < NN) sum += deg[idx];
    }
    sarr[t] = sum;
    __syncthreads();
    for (int off = 1; off < 1024; off <<= 1) {
        int v = (t >= off) ? sarr[t - off] : 0;
        __syncthreads();
        sarr[t] += v;
        __syncthreads();
    }
    int run = sarr[t] - sum;  // exclusive prefix
    for (int j = 0; j < CH; ++j) {
        int idx = base + j;
        if (idx < NN) {
            row_ptr[idx] = run;
            cursor[idx] = run;
            run += deg[idx];
        }
    }
    if (t == 0) row_ptr[NN] = ET;
}

__global__ void k_scatter(const int* __restrict__ src, const int* __restrict__ dst,
                          int* __restrict__ cursor, int* __restrict__ edge_src) {
    int i = blockIdx.x * blockDim.x + threadIdx.x;
    if (i < NE) {
        int d = dst[i];
        int pos = atomicAdd(&cursor[d], 1);
        edge_src[pos] = src[i];
    } else if (i < ET) {
        int v = i - NE;
        int pos = atomicAdd(&cursor[v], 1);
        edge_src[pos] = v;
    }
}

// ---------------- layer-0 dual GEMM (reads x directly, no BN) ----------------

template<int DIN, int DCOLS>
__global__ __launch_bounds__(256) void k_gemm3(const float* __restrict__ hin,
                                               const float* __restrict__ Wl, const float* __restrict__ bl,
                                               const float* __restrict__ Wr, const float* __restrict__ br,
                                               float* __restrict__ xl, float* __restrict__ xr) {
    constexpr int CG = (2 * DCOLS) / 64;
    constexpr int NSETS = 4 / CG;
    constexpr int NPB = NSETS * 4;
    int wave = __builtin_amdgcn_readfirstlane(threadIdx.x >> 6);
    int lane = threadIdx.x & 63;
    int cg = wave % CG;
    int nset = wave / CG;
    int col = cg * 64 + lane;
    bool isl = col < DCOLS;
    const float* W = isl ? Wl : Wr;
    float* xo = isl ? xl : xr;
    int cw = col & (DCOLS - 1);
    float wreg[DIN];
    #pragma unroll
    for (int k = 0; k < DIN; ++k) wreg[k] = W[k * DCOLS + cw];
    float bias = (isl ? bl : br)[cw];

    for (int n0 = blockIdx.x * NPB + nset * 4; n0 < NN; n0 += gridDim.x * NPB) {
        const float* h0 = hin + (size_t)n0 * DIN;
        float a0 = 0.f, a1 = 0.f, a2 = 0.f, a3 = 0.f;
        #pragma unroll
        for (int k = 0; k < DIN; ++k) {
            float wk = wreg[k];
            a0 = fmaf(h0[k],           wk, a0);
            a1 = fmaf(h0[DIN + k],     wk, a1);
            a2 = fmaf(h0[2 * DIN + k], wk, a2);
            a3 = fmaf(h0[3 * DIN + k], wk, a3);
        }
        xo[(size_t)(n0 + 0) * DCOLS + cw] = a0 + bias;
        xo[(size_t)(n0 + 1) * DCOLS + cw] = a1 + bias;
        xo[(size_t)(n0 + 2) * DCOLS + cw] = a2 + bias;
        xo[(size_t)(n0 + 3) * DCOLS + cw] = a3 + bias;
    }
}

// ---------------- fused BN-apply + dual GEMM (mid & final layers) ----------------
// Reduces 64 stat slots -> scale/shift; computes h = [hprev +] relu(scale*g+shift)
// for the node tile into LDS (+ writes hbuf for residual chain); then the
// register-resident GEMM reads h via LDS broadcast float4. Block 0 zeroes the
// next layer's partial buffer. wreg MUST stay fully unrolled (rule #20).

template<int DCOLS>
__global__ __launch_bounds__(256) void k_gemm_fused(
        const float* __restrict__ g, const float* __restrict__ part,
        float* __restrict__ partZero,
        const float* __restrict__ gam, const float* __restrict__ bet,
        int addres, float* __restrict__ hbuf,
        const float* __restrict__ Wl, const float* __restrict__ bl,
        const float* __restrict__ Wr, const float* __restrict__ br,
        float* __restrict__ xl, float* __restrict__ xr) {
    constexpr int DIN = 64;
    constexpr int CG = (2 * DCOLS) / 64;   // 4 (DCOLS=128) or 2 (DCOLS=64)
    constexpr int NSETS = 4 / CG;          // 1 or 2
    constexpr int NPB = NSETS * 4;         // 4 or 8 nodes per block-iter
    __shared__ float sscale[64], sshift[64];
    __shared__ float hlds[NPB][64];
    int tid = threadIdx.x;

    if (blockIdx.x == 0) {
        for (int i = tid; i < 64 * 128; i += 256) partZero[i] = 0.f;
    }
    // reduce stat slots: S1 (half 0), S2 (half 1)
    {
        int c = tid & 63, half = tid >> 6;
        if (half < 2) {
            float ssum = 0.f;
            for (int s = 0; s < 64; ++s) ssum += part[s * 128 + half * 64 + c];
            hlds[half][c] = ssum;
        }
    }
    __syncthreads();
    if (tid < 64) {
        float mu  = hlds[0][tid] * (1.f / NN);
        float var = hlds[1][tid] * (1.f / NN) - mu * mu;
        float sc  = gam[tid] * rsqrtf(var + BN_EPS);
        sscale[tid] = sc;
        sshift[tid] = bet[tid] - sc * mu;
    }

    int wave = __builtin_amdgcn_readfirstlane(tid >> 6);
    int lane = tid & 63;
    int cg = wave % CG;
    int nset = wave / CG;
    int col = cg * 64 + lane;
    bool isl = col < DCOLS;
    const float* W = isl ? Wl : Wr;
    float* xo = isl ? xl : xr;
    int cw = col & (DCOLS - 1);
    float wreg[DIN];
    #pragma unroll
    for (int k = 0; k < DIN; ++k) wreg[k] = W[k * DCOLS + cw];
    float bias = (isl ? bl : br)[cw];

    for (int n0 = blockIdx.x * NPB; n0 < NN; n0 += gridDim.x * NPB) {
        __syncthreads();   // previous iter's FMA reads done; hlds reusable
        #pragma unroll
        for (int v = 0; v < (NPB * 64) / 256; ++v) {
            int idx = tid + v * 256;
            int nl = idx >> 6, c = idx & 63;
            int node = n0 + nl;
            float gv = g[(size_t)node * 64 + c];
            float hv = fmaxf(fmaf(sscale[c], gv, sshift[c]), 0.f);
            if (addres) hv += hbuf[(size_t)node * 64 + c];
            hlds[nl][c] = hv;
            hbuf[(size_t)node * 64 + c] = hv;
        }
        __syncthreads();
        int nb = nset * 4;
        float a0 = 0.f, a1 = 0.f, a2 = 0.f, a3 = 0.f;
        #pragma unroll
        for (int k4 = 0; k4 < 16; ++k4) {
            float4 h0 = *(const float4*)&hlds[nb + 0][k4 * 4];
            float4 h1 = *(const float4*)&hlds[nb + 1][k4 * 4];
            float4 h2 = *(const float4*)&hlds[nb + 2][k4 * 4];
            float4 h3 = *(const float4*)&hlds[nb + 3][k4 * 4];
            a0 = fmaf(h0.x, wreg[k4*4+0], a0); a0 = fmaf(h0.y, wreg[k4*4+1], a0);
            a0 = fmaf(h0.z, wreg[k4*4+2], a0); a0 = fmaf(h0.w, wreg[k4*4+3], a0);
            a1 = fmaf(h1.x, wreg[k4*4+0], a1); a1 = fmaf(h1.y, wreg[k4*4+1], a1);
            a1 = fmaf(h1.z, wreg[k4*4+2], a1); a1 = fmaf(h1.w, wreg[k4*4+3], a1);
            a2 = fmaf(h2.x, wreg[k4*4+0], a2); a2 = fmaf(h2.y, wreg[k4*4+1], a2);
            a2 = fmaf(h2.z, wreg[k4*4+2], a2); a2 = fmaf(h2.w, wreg[k4*4+3], a2);
            a3 = fmaf(h3.x, wreg[k4*4+0], a3); a3 = fmaf(h3.y, wreg[k4*4+1], a3);
            a3 = fmaf(h3.z, wreg[k4*4+2], a3); a3 = fmaf(h3.w, wreg[k4*4+3], a3);
        }
        int nbase = n0 + nb;
        xo[(size_t)(nbase + 0) * DCOLS + cw] = a0 + bias;
        xo[(size_t)(nbase + 1) * DCOLS + cw] = a1 + bias;
        xo[(size_t)(nbase + 2) * DCOLS + cw] = a2 + bias;
        xo[(size_t)(nbase + 3) * DCOLS + cw] = a3 + bias;
    }
}

// ---------------- edge aggregation + BN stat accumulation ----------------
// One wave per node (block=64), both heads; 8-edge batches; defer-max (THR=8).
// Tail: atomicAdd g and g^2 into 64 contention-spread slots.

template<int CPL>
__global__ __launch_bounds__(64) void k_edge_stat(const float* __restrict__ xl,
                                                  const float* __restrict__ xr,
                                                  const float* __restrict__ att,
                                                  const float* __restrict__ bias,
                                                  const int* __restrict__ row_ptr,
                                                  const int* __restrict__ edge_src,
                                                  float* __restrict__ g,
                                                  float* __restrict__ partial) {
    constexpr int HC = CPL * 32;
    constexpr int RS = 2 * HC;
    int lane = threadIdx.x;
    int node = blockIdx.x;
    int co = lane * CPL;
    float2 xrv, attc;
    if (CPL == 2) {
        xrv  = *(const float2*)&xr[node * RS + co];
        attc = *(const float2*)&att[co];
    } else {
        xrv.x = xr[node * RS + co]; xrv.y = 0.f;
        attc.x = att[co];           attc.y = 0.f;
    }
    int beg = row_ptr[node], end = row_ptr[node + 1];
    float m = -1e30f, s = 0.f;
    float2 o = {0.f, 0.f};

    for (int cb = beg; cb < end; cb += 64) {
        int idx = cb + lane;
        int eload = edge_src[idx < end ? idx : end - 1];
        int cnt = min(64, end - cb);
        for (int b = 0; b < cnt; b += 8) {
            int nb = min(8, cnt - b);
            float p[8]; float2 xv[8];
            #pragma unroll
            for (int j = 0; j < 8; ++j) {
                int u = __shfl(eload, b + (j < nb ? j : 0));
                float2 v;
                if (CPL == 2) v = *(const float2*)&xl[u * RS + co];
                else { v.x = xl[u * RS + co]; v.y = 0.f; }
                xv[j] = v;
                float tx = v.x + xrv.x, ty = v.y + xrv.y;
                tx = tx > 0.f ? tx : SLOPE * tx;
                ty = ty > 0.f ? ty : SLOPE * ty;
                float pp = tx * attc.x + ty * attc.y;
                #pragma unroll
                for (int msk = 16; msk; msk >>= 1) pp += __shfl_xor(pp, msk);
                p[j] = (j < nb) ? pp : -1e30f;
            }
            float nm = fmaxf(fmaxf(fmaxf(p[0], p[1]), fmaxf(p[2], p[3])),
                             fmaxf(fmaxf(p[4], p[5]), fmaxf(p[6], p[7])));
            if (nm > m + 8.f) {
                float sc = __expf(m - nm);
                s *= sc; o.x *= sc; o.y *= sc;
                m = nm;
            }
            float w0 = __expf(p[0] - m), w1 = __expf(p[1] - m);
            float w2 = __expf(p[2] - m), w3 = __expf(p[3] - m);
            float w4 = __expf(p[4] - m), w5 = __expf(p[5] - m);
            float w6 = __expf(p[6] - m), w7 = __expf(p[7] - m);
            s += ((w0 + w1) + (w2 + w3)) + ((w4 + w5) + (w6 + w7));
            o.x += ((w0 * xv[0].x + w1 * xv[1].x) + (w2 * xv[2].x + w3 * xv[3].x))
                 + ((w4 * xv[4].x + w5 * xv[5].x) + (w6 * xv[6].x + w7 * xv[7].x));
            o.y += ((w0 * xv[0].y + w1 * xv[1].y) + (w2 * xv[2].y + w3 * xv[3].y))
                 + ((w4 * xv[4].y + w5 * xv[5].y) + (w6 * xv[6].y + w7 * xv[7].y));
        }
    }
    float inv = 1.f / s;
    float rx = o.x * inv, ry = o.y * inv;
    float ox = __shfl_xor(rx, 32);
    float oy = __shfl_xor(ry, 32);
    if (lane < 32) {
        float* ps = &partial[(size_t)(node & 63) * 128];
        if (CPL == 2) {
            float2 bv = *(const float2*)&bias[co];
            float2 outv = { 0.5f * (rx + ox) + bv.x, 0.5f * (ry + oy) + bv.y };
            *(float2*)&g[(size_t)node * HC + co] = outv;
            atomicAdd(&ps[co],     outv.x);
            atomicAdd(&ps[co + 1], outv.y);
            atomicAdd(&ps[64 + co],     outv.x * outv.x);
            atomicAdd(&ps[64 + co + 1], outv.y * outv.y);
        } else {
            float ov = 0.5f * (rx + ox) + bias[co];
            g[(size_t)node * HC + co] = ov;
            atomicAdd(&ps[co], ov);
            atomicAdd(&ps[64 + co], ov * ov);
        }
    }
}

// ---------------- final BN + two heads fused ----------------

__global__ __launch_bounds__(256) void k_headf(const float* __restrict__ g,
                                               const float* __restrict__ part,
                                               const float* __restrict__ gL, const float* __restrict__ beL,
                                               const float* __restrict__ Wimp, const float* __restrict__ bimp,
                                               const float* __restrict__ Wpol, const float* __restrict__ bpol,
                                               float* __restrict__ out) {
    __shared__ float tmp[2][32];
    __shared__ float sscale[32], sshift[32], swi[32], swp[32];
    int tid = threadIdx.x;
    if (tid < 64) {
        int c = tid & 31, half = tid >> 5;
        float ssum = 0.f;
        for (int s = 0; s < 64; ++s) ssum += part[s * 128 + half * 64 + c];
        tmp[half][c] = ssum;
    }
    __syncthreads();
    if (tid < 32) {
        float mu  = tmp[0][tid] * (1.f / NN);
        float var = tmp[1][tid] * (1.f / NN) - mu * mu;
        float sc  = gL[tid] * rsqrtf(var + BN_EPS);
        sscale[tid] = sc;
        sshift[tid] = beL[tid] - sc * mu;
        swi[tid] = Wimp[tid];
        swp[tid] = Wpol[tid];
    }
    __syncthreads();
    int n = blockIdx.x * 256 + tid;
    if (n >= NN) return;
    float a1 = bimp[0], a2 = bpol[0];
    #pragma unroll
    for (int k = 0; k < DOUTC; ++k) {
        float hv = fmaxf(fmaf(sscale[k], g[(size_t)n * DOUTC + k], sshift[k]), 0.f);
        a1 = fmaf(hv, swi[k], a1);
        a2 = fmaf(hv, swp[k], a2);
    }
    out[n] = a1;
    out[NN + n] = 1.f / (1.f + expf(-a2));
}

// ---------------- launch ----------------

extern "C" void kernel_launch(void* const* d_in, const int* in_sizes, int n_in,
                              void* d_out, int out_size, void* d_ws, size_t ws_size,
                              hipStream_t stream) {
    const float* x    = (const float*)d_in[0];
    const int*   src  = (const int*)d_in[1];
    const int*   dst  = (const int*)d_in[2];
    const float* W0l  = (const float*)d_in[3];
    const float* b0l  = (const float*)d_in[4];
    const float* W0r  = (const float*)d_in[5];
    const float* b0r  = (const float*)d_in[6];
    const float* att0 = (const float*)d_in[7];
    const float* bias0= (const float*)d_in[8];
    const float* g0   = (const float*)d_in[9];
    const float* be0  = (const float*)d_in[10];
    const float* Wml  = (const float*)d_in[11];
    const float* bml  = (const float*)d_in[12];
    const float* Wmr  = (const float*)d_in[13];
    const float* bmr  = (const float*)d_in[14];
    const float* attm = (const float*)d_in[15];
    const float* biasm= (const float*)d_in[16];
    const float* gm   = (const float*)d_in[17];
    const float* bem  = (const float*)d_in[18];
    const float* WLl  = (const float*)d_in[19];
    const float* bLl  = (const float*)d_in[20];
    const float* WLr  = (const float*)d_in[21];
    const float* bLr  = (const float*)d_in[22];
    const float* attL = (const float*)d_in[23];
    const float* biasL= (const float*)d_in[24];
    const float* gL   = (const float*)d_in[25];
    const float* beL  = (const float*)d_in[26];
    const float* Wimp = (const float*)d_in[27];
    const float* bimp = (const float*)d_in[28];
    const float* Wpol = (const float*)d_in[29];
    const float* bpol = (const float*)d_in[30];
    float* out = (float*)d_out;

    char* w = (char*)d_ws;
    size_t off = 0;
    auto alloc = [&](size_t bytes) -> char* {
        char* p = w + off;
        off += (bytes + 511) & ~(size_t)511;
        return p;
    };
    int* deg      = (int*)alloc(NN * 4);
    int* cursor   = (int*)alloc(NN * 4);
    int* row_ptr  = (int*)alloc((NN + 1) * 4);
    int* edge_src = (int*)alloc(ET * 4);
    float* xl   = (float*)alloc((size_t)NN * 128 * 4);
    float* xr   = (float*)alloc((size_t)NN * 128 * 4);
    float* gbuf = (float*)alloc((size_t)NN * 64 * 4);
    float* hbuf = (float*)alloc((size_t)NN * 64 * 4);
    float* part = (float*)alloc(2 * 64 * 128 * 4);
    float* part0 = part;
    float* part1 = part + 64 * 128;

    // preprocessing
    k_init<<<(NN + 255) / 256, 256, 0, stream>>>(deg, part);
    k_hist<<<(NE + 255) / 256, 256, 0, stream>>>(dst, deg);
    k_scan<<<1, 1024, 0, stream>>>(deg, row_ptr, cursor);
    k_scatter<<<(ET + 255) / 256, 256, 0, stream>>>(src, dst, cursor, edge_src);

    // layer 0: x [N,17] -> xl/xr [N,128]; edge -> g0, stats -> part0
    k_gemm3<FIN, 128><<<1250, 256, 0, stream>>>(x, W0l, b0l, W0r, b0r, xl, xr);
    k_edge_stat<2><<<NN, 64, 0, stream>>>(xl, xr, att0, bias0, row_ptr, edge_src, gbuf, part0);

    // layers 1..18 (mid): fused BN(g_{L-1}) + GEMM; edge -> stats
    for (int L = 1; L <= NMIDL; ++L) {
        int i = L - 1;  // mid index
        const float* pg = (L == 1) ? g0  : gm  + (size_t)(L - 2) * DD;
        const float* pb = (L == 1) ? be0 : bem + (size_t)(L - 2) * DD;
        float* pPrev = (L & 1) ? part0 : part1;   // part[(L-1)&1]
        float* pNext = (L & 1) ? part1 : part0;   // part[L&1]
        k_gemm_fused<128><<<1250, 256, 0, stream>>>(
            gbuf, pPrev, pNext, pg, pb, (L >= 2) ? 1 : 0, hbuf,
            Wml + (size_t)i * DD * 128, bml + (size_t)i * 128,
            Wmr + (size_t)i * DD * 128, bmr + (size_t)i * 128, xl, xr);
        k_edge_stat<2><<<NN, 64, 0, stream>>>(xl, xr, attm + (size_t)i * 128,
                                              biasm + (size_t)i * DD, row_ptr, edge_src, gbuf, pNext);
    }

    // layer 19 (final): fused BN(g_18) + GEMM (64 cols); edge -> stats -> part1
    {
        int L = 19;
        const float* pg = gm  + (size_t)(L - 2) * DD;   // gm[17]
        const float* pb = bem + (size_t)(L - 2) * DD;
        float* pPrev = part0;   // 18&1 == 0
        float* pNext = part1;
        k_gemm_fused<64><<<1250, 256, 0, stream>>>(
            gbuf, pPrev, pNext, pg, pb, 1, hbuf,
            WLl, bLl, WLr, bLr, xl, xr);
        k_edge_stat<1><<<NN, 64, 0, stream>>>(xl, xr, attL, biasL, row_ptr, edge_src, gbuf, pNext);
    }

    // final BN + heads
    k_headf<<<(NN + 255) / 256, 256, 0, stream>>>(gbuf, part1, gL, beL, Wimp, bimp, Wpol, bpol, out);
}

// Round 10
// 1256.057 us; speedup vs baseline: 1.7802x; 1.0891x over previous
//
#include <hip/hip_runtime.h>
#include <hip/hip_fp16.h>
#include <math.h>

#define NN 20000
#define NE 320000
#define ET (NE + NN)
#define FIN 17
#define DD 64
#define DOUTC 32
#define NMIDL 18
#define SLOPE 0.2f
#define BN_EPS 1e-5f

typedef unsigned short ushortT;
typedef unsigned int uintT;

__device__ inline ushortT f2h(float x) { return __half_as_ushort(__float2half(x)); }
__device__ inline float2 h2unpack(uintT u) {
    __half2 h2 = *(__half2*)&u;
    return __half22float2(h2);
}

// ---------------- preprocessing: CSR by dst ----------------

__global__ void k_init(int* __restrict__ deg, float* __restrict__ part) {
    int i = blockIdx.x * blockDim.x + threadIdx.x;
    if (i < NN) deg[i] = 1;              // self-loop
    if (i < 2 * 64 * 128) part[i] = 0.f; // zero both stat-partial buffers
}

__global__ void k_hist(const int* __restrict__ dst, int* __restrict__ deg) {
    int i = blockIdx.x * blockDim.x + threadIdx.x;
    if (i < NE) atomicAdd(&deg[dst[i]], 1);
}

__global__ __launch_bounds__(1024) void k_scan(const int* __restrict__ deg,
                                               int* __restrict__ row_ptr,
                                               int* __restrict__ cursor) {
    __shared__ int sarr[1024];
    int t = threadIdx.x;
    const int CH = 20;  // 1024*20 >= 20000
    int base = t * CH;
    int sum = 0;
    for (int j = 0; j < CH; ++j) {
        int idx = base + j;
        if (idx < NN) sum += deg[idx];
    }
    sarr[t] = sum;
    __syncthreads();
    for (int off = 1; off < 1024; off <<= 1) {
        int v = (t >= off) ? sarr[t - off] : 0;
        __syncthreads();
        sarr[t] += v;
        __syncthreads();
    }
    int run = sarr[t] - sum;  // exclusive prefix
    for (int j = 0; j < CH; ++j) {
        int idx = base + j;
        if (idx < NN) {
            row_ptr[idx] = run;
            cursor[idx] = run;
            run += deg[idx];
        }
    }
    if (t == 0) row_ptr[NN] = ET;
}

__global__ void k_scatter(const int* __restrict__ src, const int* __restrict__ dst,
                          int* __restrict__ cursor, int* __restrict__ edge_src) {
    int i = blockIdx.x * blockDim.x + threadIdx.x;
    if (i < NE) {
        int d = dst[i];
        int pos = atomicAdd(&cursor[d], 1);
        edge_src[pos] = src[i];
    } else if (i < ET) {
        int v = i - NE;
        int pos = atomicAdd(&cursor[v], 1);
        edge_src[pos] = v;
    }
}

// ---------------- layer-0 dual GEMM (reads x f32, writes xl/xr fp16) ----------------

template<int DIN, int DCOLS>
__global__ __launch_bounds__(256) void k_gemm3(const float* __restrict__ hin,
                                               const float* __restrict__ Wl, const float* __restrict__ bl,
                                               const float* __restrict__ Wr, const float* __restrict__ br,
                                               ushortT* __restrict__ xl, ushortT* __restrict__ xr) {
    constexpr int CG = (2 * DCOLS) / 64;
    constexpr int NSETS = 4 / CG;
    constexpr int NPB = NSETS * 4;
    int wave = __builtin_amdgcn_readfirstlane(threadIdx.x >> 6);
    int lane = threadIdx.x & 63;
    int cg = wave % CG;
    int nset = wave / CG;
    int col = cg * 64 + lane;
    bool isl = col < DCOLS;
    const float* W = isl ? Wl : Wr;
    ushortT* xo = isl ? xl : xr;
    int cw = col & (DCOLS - 1);
    float wreg[DIN];
    #pragma unroll
    for (int k = 0; k < DIN; ++k) wreg[k] = W[k * DCOLS + cw];
    float bias = (isl ? bl : br)[cw];

    for (int n0 = blockIdx.x * NPB + nset * 4; n0 < NN; n0 += gridDim.x * NPB) {
        const float* h0 = hin + (size_t)n0 * DIN;
        float a0 = 0.f, a1 = 0.f, a2 = 0.f, a3 = 0.f;
        #pragma unroll
        for (int k = 0; k < DIN; ++k) {
            float wk = wreg[k];
            a0 = fmaf(h0[k],           wk, a0);
            a1 = fmaf(h0[DIN + k],     wk, a1);
            a2 = fmaf(h0[2 * DIN + k], wk, a2);
            a3 = fmaf(h0[3 * DIN + k], wk, a3);
        }
        xo[(size_t)(n0 + 0) * DCOLS + cw] = f2h(a0 + bias);
        xo[(size_t)(n0 + 1) * DCOLS + cw] = f2h(a1 + bias);
        xo[(size_t)(n0 + 2) * DCOLS + cw] = f2h(a2 + bias);
        xo[(size_t)(n0 + 3) * DCOLS + cw] = f2h(a3 + bias);
    }
}

// ---------------- fused BN-apply + dual GEMM (mid & final layers) ----------------
// wreg MUST stay fully unrolled (rule #20: runtime-indexed arrays -> scratch).

template<int DCOLS>
__global__ __launch_bounds__(256) void k_gemm_fused(
        const float* __restrict__ g, const float* __restrict__ part,
        float* __restrict__ partZero,
        const float* __restrict__ gam, const float* __restrict__ bet,
        int addres, float* __restrict__ hbuf,
        const float* __restrict__ Wl, const float* __restrict__ bl,
        const float* __restrict__ Wr, const float* __restrict__ br,
        ushortT* __restrict__ xl, ushortT* __restrict__ xr) {
    constexpr int DIN = 64;
    constexpr int CG = (2 * DCOLS) / 64;   // 4 (DCOLS=128) or 2 (DCOLS=64)
    constexpr int NSETS = 4 / CG;          // 1 or 2
    constexpr int NPB = NSETS * 4;         // 4 or 8 nodes per block-iter
    __shared__ float sscale[64], sshift[64];
    __shared__ float hlds[NPB][64];
    int tid = threadIdx.x;

    if (blockIdx.x == 0) {
        for (int i = tid; i < 64 * 128; i += 256) partZero[i] = 0.f;
    }
    // reduce stat slots: S1 (half 0), S2 (half 1)
    {
        int c = tid & 63, half = tid >> 6;
        if (half < 2) {
            float ssum = 0.f;
            for (int s = 0; s < 64; ++s) ssum += part[s * 128 + half * 64 + c];
            hlds[half][c] = ssum;
        }
    }
    __syncthreads();
    if (tid < 64) {
        float mu  = hlds[0][tid] * (1.f / NN);
        float var = hlds[1][tid] * (1.f / NN) - mu * mu;
        float sc  = gam[tid] * rsqrtf(var + BN_EPS);
        sscale[tid] = sc;
        sshift[tid] = bet[tid] - sc * mu;
    }

    int wave = __builtin_amdgcn_readfirstlane(tid >> 6);
    int lane = tid & 63;
    int cg = wave % CG;
    int nset = wave / CG;
    int col = cg * 64 + lane;
    bool isl = col < DCOLS;
    const float* W = isl ? Wl : Wr;
    ushortT* xo = isl ? xl : xr;
    int cw = col & (DCOLS - 1);
    float wreg[DIN];
    #pragma unroll
    for (int k = 0; k < DIN; ++k) wreg[k] = W[k * DCOLS + cw];
    float bias = (isl ? bl : br)[cw];

    for (int n0 = blockIdx.x * NPB; n0 < NN; n0 += gridDim.x * NPB) {
        __syncthreads();
        #pragma unroll
        for (int v = 0; v < (NPB * 64) / 256; ++v) {
            int idx = tid + v * 256;
            int nl = idx >> 6, c = idx & 63;
            int node = n0 + nl;
            float gv = g[(size_t)node * 64 + c];
            float hv = fmaxf(fmaf(sscale[c], gv, sshift[c]), 0.f);
            if (addres) hv += hbuf[(size_t)node * 64 + c];
            hlds[nl][c] = hv;
            hbuf[(size_t)node * 64 + c] = hv;
        }
        __syncthreads();
        int nb = nset * 4;
        float a0 = 0.f, a1 = 0.f, a2 = 0.f, a3 = 0.f;
        #pragma unroll
        for (int k4 = 0; k4 < 16; ++k4) {
            float4 h0 = *(const float4*)&hlds[nb + 0][k4 * 4];
            float4 h1 = *(const float4*)&hlds[nb + 1][k4 * 4];
            float4 h2 = *(const float4*)&hlds[nb + 2][k4 * 4];
            float4 h3 = *(const float4*)&hlds[nb + 3][k4 * 4];
            a0 = fmaf(h0.x, wreg[k4*4+0], a0); a0 = fmaf(h0.y, wreg[k4*4+1], a0);
            a0 = fmaf(h0.z, wreg[k4*4+2], a0); a0 = fmaf(h0.w, wreg[k4*4+3], a0);
            a1 = fmaf(h1.x, wreg[k4*4+0], a1); a1 = fmaf(h1.y, wreg[k4*4+1], a1);
            a1 = fmaf(h1.z, wreg[k4*4+2], a1); a1 = fmaf(h1.w, wreg[k4*4+3], a1);
            a2 = fmaf(h2.x, wreg[k4*4+0], a2); a2 = fmaf(h2.y, wreg[k4*4+1], a2);
            a2 = fmaf(h2.z, wreg[k4*4+2], a2); a2 = fmaf(h2.w, wreg[k4*4+3], a2);
            a3 = fmaf(h3.x, wreg[k4*4+0], a3); a3 = fmaf(h3.y, wreg[k4*4+1], a3);
            a3 = fmaf(h3.z, wreg[k4*4+2], a3); a3 = fmaf(h3.w, wreg[k4*4+3], a3);
        }
        int nbase = n0 + nb;
        xo[(size_t)(nbase + 0) * DCOLS + cw] = f2h(a0 + bias);
        xo[(size_t)(nbase + 1) * DCOLS + cw] = f2h(a1 + bias);
        xo[(size_t)(nbase + 2) * DCOLS + cw] = f2h(a2 + bias);
        xo[(size_t)(nbase + 3) * DCOLS + cw] = f2h(a3 + bias);
    }
}

// ---------------- edge aggregation + BN stat accumulation (fp16 gathers) ----------------
// One wave per node (block=64), both heads; 8-edge batches; defer-max (THR=8).
// CPL=2: lane loads one uint = 2 fp16 channels (half the L3 bytes of f32).

template<int CPL>
__global__ __launch_bounds__(64) void k_edge_stat(const ushortT* __restrict__ xl,
                                                  const ushortT* __restrict__ xr,
                                                  const float* __restrict__ att,
                                                  const float* __restrict__ bias,
                                                  const int* __restrict__ row_ptr,
                                                  const int* __restrict__ edge_src,
                                                  float* __restrict__ g,
                                                  float* __restrict__ partial) {
    constexpr int HC = CPL * 32;
    constexpr int RS = 2 * HC;     // row length in fp16 elems
    int lane = threadIdx.x;
    int node = blockIdx.x;
    int co = lane * CPL;
    float2 xrv, attc;
    if (CPL == 2) {
        uintT ur = ((const uintT*)xr)[(size_t)node * (RS / 2) + lane];
        xrv = h2unpack(ur);
        attc = *(const float2*)&att[co];
    } else {
        xrv.x = __half2float(__ushort_as_half(xr[(size_t)node * RS + co]));
        xrv.y = 0.f;
        attc.x = att[co];
        attc.y = 0.f;
    }
    int beg = row_ptr[node], end = row_ptr[node + 1];
    float m = -1e30f, s = 0.f;
    float2 o = {0.f, 0.f};

    for (int cb = beg; cb < end; cb += 64) {
        int idx = cb + lane;
        int eload = edge_src[idx < end ? idx : end - 1];
        int cnt = min(64, end - cb);
        for (int b = 0; b < cnt; b += 8) {
            int nb = min(8, cnt - b);
            float p[8]; float2 xv[8];
            #pragma unroll
            for (int j = 0; j < 8; ++j) {
                int u = __shfl(eload, b + (j < nb ? j : 0));
                float2 v;
                if (CPL == 2) {
                    uintT uu = ((const uintT*)xl)[(size_t)u * (RS / 2) + lane];
                    v = h2unpack(uu);
                } else {
                    v.x = __half2float(__ushort_as_half(xl[(size_t)u * RS + co]));
                    v.y = 0.f;
                }
                xv[j] = v;
                float tx = v.x + xrv.x, ty = v.y + xrv.y;
                tx = tx > 0.f ? tx : SLOPE * tx;
                ty = ty > 0.f ? ty : SLOPE * ty;
                float pp = tx * attc.x + ty * attc.y;
                #pragma unroll
                for (int msk = 16; msk; msk >>= 1) pp += __shfl_xor(pp, msk);
                p[j] = (j < nb) ? pp : -1e30f;
            }
            float nm = fmaxf(fmaxf(fmaxf(p[0], p[1]), fmaxf(p[2], p[3])),
                             fmaxf(fmaxf(p[4], p[5]), fmaxf(p[6], p[7])));
            if (nm > m + 8.f) {
                float sc = __expf(m - nm);
                s *= sc; o.x *= sc; o.y *= sc;
                m = nm;
            }
            float w0 = __expf(p[0] - m), w1 = __expf(p[1] - m);
            float w2 = __expf(p[2] - m), w3 = __expf(p[3] - m);
            float w4 = __expf(p[4] - m), w5 = __expf(p[5] - m);
            float w6 = __expf(p[6] - m), w7 = __expf(p[7] - m);
            s += ((w0 + w1) + (w2 + w3)) + ((w4 + w5) + (w6 + w7));
            o.x += ((w0 * xv[0].x + w1 * xv[1].x) + (w2 * xv[2].x + w3 * xv[3].x))
                 + ((w4 * xv[4].x + w5 * xv[5].x) + (w6 * xv[6].x + w7 * xv[7].x));
            o.y += ((w0 * xv[0].y + w1 * xv[1].y) + (w2 * xv[2].y + w3 * xv[3].y))
                 + ((w4 * xv[4].y + w5 * xv[5].y) + (w6 * xv[6].y + w7 * xv[7].y));
        }
    }
    float inv = 1.f / s;
    float rx = o.x * inv, ry = o.y * inv;
    float ox = __shfl_xor(rx, 32);
    float oy = __shfl_xor(ry, 32);
    if (lane < 32) {
        float* ps = &partial[(size_t)(node & 63) * 128];
        if (CPL == 2) {
            float2 bv = *(const float2*)&bias[co];
            float2 outv = { 0.5f * (rx + ox) + bv.x, 0.5f * (ry + oy) + bv.y };
            *(float2*)&g[(size_t)node * HC + co] = outv;
            atomicAdd(&ps[co],     outv.x);
            atomicAdd(&ps[co + 1], outv.y);
            atomicAdd(&ps[64 + co],     outv.x * outv.x);
            atomicAdd(&ps[64 + co + 1], outv.y * outv.y);
        } else {
            float ov = 0.5f * (rx + ox) + bias[co];
            g[(size_t)node * HC + co] = ov;
            atomicAdd(&ps[co], ov);
            atomicAdd(&ps[64 + co], ov * ov);
        }
    }
}

// ---------------- final BN + two heads fused ----------------

__global__ __launch_bounds__(256) void k_headf(const float* __restrict__ g,
                                               const float* __restrict__ part,
                                               const float* __restrict__ gL, const float* __restrict__ beL,
                                               const float* __restrict__ Wimp, const float* __restrict__ bimp,
                                               const float* __restrict__ Wpol, const float* __restrict__ bpol,
                                               float* __restrict__ out) {
    __shared__ float tmp[2][32];
    __shared__ float sscale[32], sshift[32], swi[32], swp[32];
    int tid = threadIdx.x;
    if (tid < 64) {
        int c = tid & 31, half = tid >> 5;
        float ssum = 0.f;
        for (int s = 0; s < 64; ++s) ssum += part[s * 128 + half * 64 + c];
        tmp[half][c] = ssum;
    }
    __syncthreads();
    if (tid < 32) {
        float mu  = tmp[0][tid] * (1.f / NN);
        float var = tmp[1][tid] * (1.f / NN) - mu * mu;
        float sc  = gL[tid] * rsqrtf(var + BN_EPS);
        sscale[tid] = sc;
        sshift[tid] = beL[tid] - sc * mu;
        swi[tid] = Wimp[tid];
        swp[tid] = Wpol[tid];
    }
    __syncthreads();
    int n = blockIdx.x * 256 + tid;
    if (n >= NN) return;
    float a1 = bimp[0], a2 = bpol[0];
    #pragma unroll
    for (int k = 0; k < DOUTC; ++k) {
        float hv = fmaxf(fmaf(sscale[k], g[(size_t)n * DOUTC + k], sshift[k]), 0.f);
        a1 = fmaf(hv, swi[k], a1);
        a2 = fmaf(hv, swp[k], a2);
    }
    out[n] = a1;
    out[NN + n] = 1.f / (1.f + expf(-a2));
}

// ---------------- launch ----------------

extern "C" void kernel_launch(void* const* d_in, const int* in_sizes, int n_in,
                              void* d_out, int out_size, void* d_ws, size_t ws_size,
                              hipStream_t stream) {
    const float* x    = (const float*)d_in[0];
    const int*   src  = (const int*)d_in[1];
    const int*   dst  = (const int*)d_in[2];
    const float* W0l  = (const float*)d_in[3];
    const float* b0l  = (const float*)d_in[4];
    const float* W0r  = (const float*)d_in[5];
    const float* b0r  = (const float*)d_in[6];
    const float* att0 = (const float*)d_in[7];
    const float* bias0= (const float*)d_in[8];
    const float* g0   = (const float*)d_in[9];
    const float* be0  = (const float*)d_in[10];
    const float* Wml  = (const float*)d_in[11];
    const float* bml  = (const float*)d_in[12];
    const float* Wmr  = (const float*)d_in[13];
    const float* bmr  = (const float*)d_in[14];
    const float* attm = (const float*)d_in[15];
    const float* biasm= (const float*)d_in[16];
    const float* gm   = (const float*)d_in[17];
    const float* bem  = (const float*)d_in[18];
    const float* WLl  = (const float*)d_in[19];
    const float* bLl  = (const float*)d_in[20];
    const float* WLr  = (const float*)d_in[21];
    const float* bLr  = (const float*)d_in[22];
    const float* attL = (const float*)d_in[23];
    const float* biasL= (const float*)d_in[24];
    const float* gL   = (const float*)d_in[25];
    const float* beL  = (const float*)d_in[26];
    const float* Wimp = (const float*)d_in[27];
    const float* bimp = (const float*)d_in[28];
    const float* Wpol = (const float*)d_in[29];
    const float* bpol = (const float*)d_in[30];
    float* out = (float*)d_out;

    char* w = (char*)d_ws;
    size_t off = 0;
    auto alloc = [&](size_t bytes) -> char* {
        char* p = w + off;
        off += (bytes + 511) & ~(size_t)511;
        return p;
    };
    int* deg      = (int*)alloc(NN * 4);
    int* cursor   = (int*)alloc(NN * 4);
    int* row_ptr  = (int*)alloc((NN + 1) * 4);
    int* edge_src = (int*)alloc(ET * 4);
    ushortT* xl = (ushortT*)alloc((size_t)NN * 128 * 2);
    ushortT* xr = (ushortT*)alloc((size_t)NN * 128 * 2);
    float* gbuf = (float*)alloc((size_t)NN * 64 * 4);
    float* hbuf = (float*)alloc((size_t)NN * 64 * 4);
    float* part = (float*)alloc(2 * 64 * 128 * 4);
    float* part0 = part;
    float* part1 = part + 64 * 128;

    // preprocessing
    k_init<<<(NN + 255) / 256, 256, 0, stream>>>(deg, part);
    k_hist<<<(NE + 255) / 256, 256, 0, stream>>>(dst, deg);
    k_scan<<<1, 1024, 0, stream>>>(deg, row_ptr, cursor);
    k_scatter<<<(ET + 255) / 256, 256, 0, stream>>>(src, dst, cursor, edge_src);

    // layer 0: x [N,17] -> xl/xr [N,128] fp16; edge -> g, stats -> part0
    k_gemm3<FIN, 128><<<1250, 256, 0, stream>>>(x, W0l, b0l, W0r, b0r, xl, xr);
    k_edge_stat<2><<<NN, 64, 0, stream>>>(xl, xr, att0, bias0, row_ptr, edge_src, gbuf, part0);

    // layers 1..18 (mid): fused BN(g_{L-1}) + GEMM; edge -> stats
    for (int L = 1; L <= NMIDL; ++L) {
        int i = L - 1;  // mid index
        const float* pg = (L == 1) ? g0  : gm  + (size_t)(L - 2) * DD;
        const float* pb = (L == 1) ? be0 : bem + (size_t)(L - 2) * DD;
        float* pPrev = (L & 1) ? part0 : part1;
        float* pNext = (L & 1) ? part1 : part0;
        k_gemm_fused<128><<<1250, 256, 0, stream>>>(
            gbuf, pPrev, pNext, pg, pb, (L >= 2) ? 1 : 0, hbuf,
            Wml + (size_t)i * DD * 128, bml + (size_t)i * 128,
            Wmr + (size_t)i * DD * 128, bmr + (size_t)i * 128, xl, xr);
        k_edge_stat<2><<<NN, 64, 0, stream>>>(xl, xr, attm + (size_t)i * 128,
                                              biasm + (size_t)i * DD, row_ptr, edge_src, gbuf, pNext);
    }

    // layer 19 (final): fused BN(g_18) + GEMM (64 cols); edge -> stats -> part1
    {
        int L = 19;
        const float* pg = gm  + (size_t)(L - 2) * DD;   // gm[17]
        const float* pb = bem + (size_t)(L - 2) * DD;
        float* pPrev = part0;   // 18&1 == 0
        float* pNext = part1;
        k_gemm_fused<64><<<1250, 256, 0, stream>>>(
            gbuf, pPrev, pNext, pg, pb, 1, hbuf,
            WLl, bLl, WLr, bLr, xl, xr);
        k_edge_stat<1><<<NN, 64, 0, stream>>>(xl, xr, attL, biasL, row_ptr, edge_src, gbuf, pNext);
    }

    // final BN + heads
    k_headf<<<(NN + 255) / 256, 256, 0, stream>>>(gbuf, part1, gL, beL, Wimp, bimp, Wpol, bpol, out);
}